// Round 4
// baseline (117.793 us; speedup 1.0000x reference)
//
#include <hip/hip_runtime.h>
#include <hip/hip_cooperative_groups.h>

namespace cg = cooperative_groups;

#define OC 1024
#define ICN 1024
#define KK 9
#define NELEM (OC * ICN * KK)
#define CH (ICN * KK)      // 9216 floats per channel
#define CH4 (CH / 4)       // 2304
#define BT 512             // 8 waves/block -> 4 blocks/CU at <=64 VGPR
#define KMB 1024           // kmax blocks (fallback path)

// ============================================================================
// Fused cooperative kernel: absmax + grid.sync + quant/stage1/stage2/store.
// x is read ONCE (cached in 18 registers/thread across the grid barrier).
// ============================================================================
__global__ void __launch_bounds__(BT, 8) fused_kernel(const float* __restrict__ x,
                                                      float* __restrict__ out,
                                                      float* __restrict__ part) {
    __shared__ __align__(16) short s_q[CH];   // 18 KB quantized values
    __shared__ float s_res[ICN];
    __shared__ float s_prio[ICN];
    __shared__ int   s_meta[ICN];
    __shared__ float s_mx[8];

    const int oc = blockIdx.x;
    const int t  = threadIdx.x;
    const long long ocbase = (long long)oc * CH;

    // ---- phase 1: load 18 elems into registers, block absmax -> part[oc] ----
    float xr[2][KK];
    {
        const float* p0 = x + ocbase + t * KK;
        const float* p1 = x + ocbase + (t + BT) * KK;
        #pragma unroll
        for (int k = 0; k < KK; ++k) xr[0][k] = p0[k];
        #pragma unroll
        for (int k = 0; k < KK; ++k) xr[1][k] = p1[k];
    }
    float m = 0.f;
    #pragma unroll
    for (int k = 0; k < KK; ++k)
        m = fmaxf(m, fmaxf(fabsf(xr[0][k]), fabsf(xr[1][k])));
    #pragma unroll
    for (int off = 32; off > 0; off >>= 1)
        m = fmaxf(m, __shfl_xor(m, off, 64));
    if ((t & 63) == 0) s_mx[t >> 6] = m;
    __syncthreads();
    if (t == 0) {
        m = s_mx[0];
        #pragma unroll
        for (int w = 1; w < 8; ++w) m = fmaxf(m, s_mx[w]);
        part[oc] = m;
        __threadfence();  // device-scope visibility before grid barrier
    }

    cg::this_grid().sync();

    // ---- phase 2: global max from 1024 partials (L2-hot 4 KB) ----
    float gm = fmaxf(part[t], part[t + BT]);
    #pragma unroll
    for (int off = 32; off > 0; off >>= 1)
        gm = fmaxf(gm, __shfl_xor(gm, off, 64));
    if ((t & 63) == 0) s_mx[t >> 6] = gm;
    __syncthreads();
    gm = s_mx[0];
    #pragma unroll
    for (int w = 1; w < 8; ++w) gm = fmaxf(gm, s_mx[w]);
    const float scale = gm / 127.0f;
    const float iscale = 1.0f / scale;  // mul not div: bit-identical in practice (R3: absmax 0.0)

    // ---- stage 1: rows t and t+BT, from registers ----
    #pragma unroll
    for (int half = 0; half < 2; ++half) {
        const int row = t + half * BT;
        float rn[KK], re[KK];
        float e = 0.f;
        #pragma unroll
        for (int k = 0; k < KK; ++k) {
            float q = xr[half][k] * iscale;
            q = fminf(fmaxf(q, -127.f), 127.f);
            float r = rintf(q);                 // round half to even
            rn[k] = r;
            re[k] = r - q;
            e += re[k];
        }
        int nf = (int)rintf(fabsf(e));
        bool up = e < 0.f;
        unsigned flipped = 0u;
        int bidx = -1;
        float b_re = 0.f;
        for (int f = 0; f < nf; ++f) {
            float bp = 0.f; int bk = -1; float cre = 0.f;
            #pragma unroll
            for (int k = 0; k < KK; ++k) {
                bool cand = up ? (re[k] < 0.f) : (re[k] > 0.f);
                float p = (cand && !((flipped >> k) & 1u)) ? fabsf(re[k]) : 0.f;
                if (p > bp) { bp = p; bk = k; cre = re[k]; }  // strict >: lowest idx wins ties
            }
            if (bk < 0) break;  // safety
            flipped |= (1u << bk);
            bidx = bk; b_re = cre;
        }
        int cnt = __popc(flipped);
        float sgn = up ? 1.f : -1.f;

        #pragma unroll
        for (int k = 0; k < KK; ++k) {
            float v = rn[k] + (((flipped >> k) & 1u) ? sgn : 0.f);
            s_q[row * KK + k] = (short)(int)v;
        }
        s_res[row] = e + sgn * (float)cnt;
        if (bidx >= 0) {
            s_prio[row] = fabsf(b_re + sgn);
            s_meta[row] = (row * KK + bidx) | ((up ? 1 : 0) << 16);
        } else {
            s_prio[row] = 0.f;
            s_meta[row] = 0;
        }
    }
    __syncthreads();

    // ---- stage 2: wave 0 only ----
    if (t < 64) {
        float s = 0.f;
        #pragma unroll
        for (int i = 0; i < ICN / 64; ++i) s += s_res[t + i * 64];
        #pragma unroll
        for (int off = 32; off > 0; off >>= 1) s += __shfl_xor(s, off, 64);

        int n2 = (int)rintf(fabsf(s));
        bool up2 = s < 0.f;
        if (n2 > 0) {
            float p[ICN / 64];
            #pragma unroll
            for (int i = 0; i < ICN / 64; ++i) {
                int r = t + i * 64;
                float pr = s_prio[r];
                int dir = s_meta[r] >> 16;
                bool match = ((dir != 0) != up2);
                p[i] = (pr > 0.f && match) ? pr : 0.f;
            }
            int f = 0;
            for (; f < n2; ++f) {
                float bp = 0.f; int brow = ICN;
                #pragma unroll
                for (int i = 0; i < ICN / 64; ++i)
                    if (p[i] > bp) { bp = p[i]; brow = t + i * 64; }
                #pragma unroll
                for (int off = 32; off > 0; off >>= 1) {
                    float op = __shfl_xor(bp, off, 64);
                    int  orow = __shfl_xor(brow, off, 64);
                    if (op > bp || (op == bp && orow < brow)) { bp = op; brow = orow; }
                }
                if (bp <= 0.f) break;
                if (t == (brow & 63)) {
                    #pragma unroll
                    for (int i = 0; i < ICN / 64; ++i)
                        if (i == (brow >> 6)) p[i] = 0.f;
                }
                if (t == 0) {
                    int meta = s_meta[brow];
                    int gid = meta & 0xFFFF;
                    s_q[gid] = (short)(s_q[gid] + ((meta >> 16) ? -1 : 1));
                }
            }
            if (f < n2) {  // dead overflow path; deviation <= 1 step
                int remaining = n2 - f;
                if (remaining > CH) remaining = CH;
                for (int j = t; j < remaining; j += 64) {
                    float q = x[ocbase + j] * iscale;
                    q = fminf(fmaxf(q, -127.f), 127.f);
                    float r = rintf(q);
                    float rr = r - q;
                    float v = up2 ? ((rr < 0.f) ? r + 1.f : r)
                                  : ((rr > 0.f) ? r - 1.f : r);
                    s_q[j] = (short)(int)v;
                }
            }
        }
    }
    __syncthreads();

    // ---- coalesced stage-out ----
    const short4* q4 = (const short4*)s_q;
    float4* o4 = (float4*)(out + ocbase);
    for (int i = t; i < CH4; i += BT) {
        short4 v = q4[i];
        float4 o;
        o.x = (float)v.x * scale;
        o.y = (float)v.y * scale;
        o.z = (float)v.z * scale;
        o.w = (float)v.w * scale;
        o4[i] = o;
    }
}

// ============================================================================
// Fallback path (R3): separate kmax + squant kernels
// ============================================================================
__global__ void __launch_bounds__(256) kmax_part(const float* __restrict__ x,
                                                 float* __restrict__ part) {
    __shared__ float s_m[4];
    const int tid = blockIdx.x * 256 + threadIdx.x;
    const int stride = KMB * 256;
    const float4* x4 = (const float4*)x;
    float m = 0.f;
    #pragma unroll
    for (int k = 0; k < 9; ++k) {
        float4 v = x4[tid + k * stride];
        m = fmaxf(m, fmaxf(fmaxf(fabsf(v.x), fabsf(v.y)), fmaxf(fabsf(v.z), fabsf(v.w))));
    }
    #pragma unroll
    for (int off = 32; off > 0; off >>= 1)
        m = fmaxf(m, __shfl_xor(m, off, 64));
    if ((threadIdx.x & 63) == 0) s_m[threadIdx.x >> 6] = m;
    __syncthreads();
    if (threadIdx.x == 0)
        part[blockIdx.x] = fmaxf(fmaxf(s_m[0], s_m[1]), fmaxf(s_m[2], s_m[3]));
}

__global__ void __launch_bounds__(256) kmax_atomic(const float* __restrict__ x,
                                                   unsigned* __restrict__ ws) {
    __shared__ float s_m[4];
    const int tid = blockIdx.x * 256 + threadIdx.x;
    const int stride = KMB * 256;
    const float4* x4 = (const float4*)x;
    float m = 0.f;
    #pragma unroll
    for (int k = 0; k < 9; ++k) {
        float4 v = x4[tid + k * stride];
        m = fmaxf(m, fmaxf(fmaxf(fabsf(v.x), fabsf(v.y)), fmaxf(fabsf(v.z), fabsf(v.w))));
    }
    #pragma unroll
    for (int off = 32; off > 0; off >>= 1)
        m = fmaxf(m, __shfl_xor(m, off, 64));
    if ((threadIdx.x & 63) == 0) s_m[threadIdx.x >> 6] = m;
    __syncthreads();
    if (threadIdx.x == 0) {
        m = fmaxf(fmaxf(s_m[0], s_m[1]), fmaxf(s_m[2], s_m[3]));
        atomicMax(ws, __float_as_uint(m));
    }
}

__global__ void __launch_bounds__(BT, 8) squant_kernel(const float* __restrict__ x,
                                                       float* __restrict__ out,
                                                       const float* __restrict__ part,
                                                       int nparts) {
    __shared__ __align__(16) short s_q[CH];
    __shared__ float s_res[ICN];
    __shared__ float s_prio[ICN];
    __shared__ int   s_meta[ICN];
    __shared__ float s_mx[8];

    const int oc = blockIdx.x;
    const int t  = threadIdx.x;
    const long long ocbase = (long long)oc * CH;

    float m;
    if (nparts > 0) {
        m = fmaxf(part[t], part[t + BT]);
        #pragma unroll
        for (int off = 32; off > 0; off >>= 1)
            m = fmaxf(m, __shfl_xor(m, off, 64));
        if ((t & 63) == 0) s_mx[t >> 6] = m;
    } else if (t == 0) {
        s_mx[0] = __uint_as_float(((const unsigned*)part)[0]);
    }
    __syncthreads();
    if (nparts > 0) {
        m = s_mx[0];
        #pragma unroll
        for (int w = 1; w < 8; ++w) m = fmaxf(m, s_mx[w]);
    } else {
        m = s_mx[0];
    }
    const float scale = m / 127.0f;
    const float iscale = 1.0f / scale;

    #pragma unroll
    for (int half = 0; half < 2; ++half) {
        const int row = t + half * BT;
        const float* px = x + ocbase + row * KK;
        float rn[KK], re[KK];
        float e = 0.f;
        #pragma unroll
        for (int k = 0; k < KK; ++k) {
            float q = px[k] * iscale;
            q = fminf(fmaxf(q, -127.f), 127.f);
            float r = rintf(q);
            rn[k] = r;
            re[k] = r - q;
            e += re[k];
        }
        int nf = (int)rintf(fabsf(e));
        bool up = e < 0.f;
        unsigned flipped = 0u;
        int bidx = -1;
        float b_re = 0.f;
        for (int f = 0; f < nf; ++f) {
            float bp = 0.f; int bk = -1; float cre = 0.f;
            #pragma unroll
            for (int k = 0; k < KK; ++k) {
                bool cand = up ? (re[k] < 0.f) : (re[k] > 0.f);
                float p = (cand && !((flipped >> k) & 1u)) ? fabsf(re[k]) : 0.f;
                if (p > bp) { bp = p; bk = k; cre = re[k]; }
            }
            if (bk < 0) break;
            flipped |= (1u << bk);
            bidx = bk; b_re = cre;
        }
        int cnt = __popc(flipped);
        float sgn = up ? 1.f : -1.f;

        #pragma unroll
        for (int k = 0; k < KK; ++k) {
            float v = rn[k] + (((flipped >> k) & 1u) ? sgn : 0.f);
            s_q[row * KK + k] = (short)(int)v;
        }
        s_res[row] = e + sgn * (float)cnt;
        if (bidx >= 0) {
            s_prio[row] = fabsf(b_re + sgn);
            s_meta[row] = (row * KK + bidx) | ((up ? 1 : 0) << 16);
        } else {
            s_prio[row] = 0.f;
            s_meta[row] = 0;
        }
    }
    __syncthreads();

    if (t < 64) {
        float s = 0.f;
        #pragma unroll
        for (int i = 0; i < ICN / 64; ++i) s += s_res[t + i * 64];
        #pragma unroll
        for (int off = 32; off > 0; off >>= 1) s += __shfl_xor(s, off, 64);

        int n2 = (int)rintf(fabsf(s));
        bool up2 = s < 0.f;
        if (n2 > 0) {
            float p[ICN / 64];
            #pragma unroll
            for (int i = 0; i < ICN / 64; ++i) {
                int r = t + i * 64;
                float pr = s_prio[r];
                int dir = s_meta[r] >> 16;
                bool match = ((dir != 0) != up2);
                p[i] = (pr > 0.f && match) ? pr : 0.f;
            }
            int f = 0;
            for (; f < n2; ++f) {
                float bp = 0.f; int brow = ICN;
                #pragma unroll
                for (int i = 0; i < ICN / 64; ++i)
                    if (p[i] > bp) { bp = p[i]; brow = t + i * 64; }
                #pragma unroll
                for (int off = 32; off > 0; off >>= 1) {
                    float op = __shfl_xor(bp, off, 64);
                    int  orow = __shfl_xor(brow, off, 64);
                    if (op > bp || (op == bp && orow < brow)) { bp = op; brow = orow; }
                }
                if (bp <= 0.f) break;
                if (t == (brow & 63)) {
                    #pragma unroll
                    for (int i = 0; i < ICN / 64; ++i)
                        if (i == (brow >> 6)) p[i] = 0.f;
                }
                if (t == 0) {
                    int meta = s_meta[brow];
                    int gid = meta & 0xFFFF;
                    s_q[gid] = (short)(s_q[gid] + ((meta >> 16) ? -1 : 1));
                }
            }
            if (f < n2) {
                int remaining = n2 - f;
                if (remaining > CH) remaining = CH;
                for (int j = t; j < remaining; j += 64) {
                    float q = x[ocbase + j] * iscale;
                    q = fminf(fmaxf(q, -127.f), 127.f);
                    float r = rintf(q);
                    float rr = r - q;
                    float v = up2 ? ((rr < 0.f) ? r + 1.f : r)
                                  : ((rr > 0.f) ? r - 1.f : r);
                    s_q[j] = (short)(int)v;
                }
            }
        }
    }
    __syncthreads();

    const short4* q4 = (const short4*)s_q;
    float4* o4 = (float4*)(out + ocbase);
    for (int i = t; i < CH4; i += BT) {
        short4 v = q4[i];
        float4 o;
        o.x = (float)v.x * scale;
        o.y = (float)v.y * scale;
        o.z = (float)v.z * scale;
        o.w = (float)v.w * scale;
        o4[i] = o;
    }
}

extern "C" void kernel_launch(void* const* d_in, const int* in_sizes, int n_in,
                              void* d_out, int out_size, void* d_ws, size_t ws_size,
                              hipStream_t stream) {
    const float* x = (const float*)d_in[0];
    float* out = (float*)d_out;

    // Capture-safe pure queries: decide path deterministically each call.
    int maxb = 0;
    hipError_t qe = hipOccupancyMaxActiveBlocksPerMultiprocessor(
        &maxb, fused_kernel, BT, 0);
    bool coop_ok = (qe == hipSuccess) && (maxb >= 4) &&
                   (ws_size >= OC * sizeof(float));

    if (coop_ok) {
        float* part = (float*)d_ws;
        void* args[] = { (void*)&x, (void*)&out, (void*)&part };
        hipError_t le = hipLaunchCooperativeKernel((const void*)fused_kernel,
                                                   dim3(OC), dim3(BT), args, 0, stream);
        if (le == hipSuccess) return;
    }

    // Fallback: two-kernel path (R3, verified exact)
    if (ws_size >= KMB * sizeof(float)) {
        float* part = (float*)d_ws;
        kmax_part<<<KMB, 256, 0, stream>>>(x, part);
        squant_kernel<<<OC, BT, 0, stream>>>(x, out, part, KMB);
    } else {
        unsigned* wsmax = (unsigned*)d_ws;
        hipMemsetAsync(d_ws, 0, 4, stream);
        kmax_atomic<<<KMB, 256, 0, stream>>>(x, wsmax);
        squant_kernel<<<OC, BT, 0, stream>>>(x, out, (const float*)d_ws, 0);
    }
}